// Round 1
// baseline (841.998 us; speedup 1.0000x reference)
//
#include <hip/hip_runtime.h>
#include <stdint.h>

#define NHEADS 12
#define STR 72   // LDS row stride in bf16 elems: 64 + 8 pad (16B-aligned, breaks bank conflicts)

typedef __bf16 bf16_t;
typedef bf16_t bx8 __attribute__((ext_vector_type(8)));
typedef float  fx4 __attribute__((ext_vector_type(4)));

// ---------------------------------------------------------------------------
// fp32 -> bf16 weight conversion into workspace.
// Layout in ws (bf16 elems): Wq[12*4096] | Wk | Wv | Wo[768*768] | attn[100352*768]
// Total elems to convert = 3*49152 + 589824 = 737280; 92160 threads x 8 = exact.
// ---------------------------------------------------------------------------
__global__ __launch_bounds__(256) void convert_w(
    const float* __restrict__ wq, const float* __restrict__ wk,
    const float* __restrict__ wv, const float* __restrict__ wo,
    bf16_t* __restrict__ dst)
{
    const int i = (blockIdx.x * 256 + threadIdx.x) * 8;
    const float* src;
    int off;
    if (i < 49152)       { src = wq; off = i; }
    else if (i < 98304)  { src = wk; off = i - 49152; }
    else if (i < 147456) { src = wv; off = i - 98304; }
    else                 { src = wo; off = i - 147456; }
    bx8 t;
    #pragma unroll
    for (int j = 0; j < 8; j++) t[j] = (bf16_t)src[off + j];
    *(bx8*)&dst[i] = t;
}

// ---------------------------------------------------------------------------
// Fused per-(window, head) attention. Block = (n, h); 256 threads = 4 waves.
// 64x64 padded tiles (rows/cols 49..63 zero). MFMA 16x16x32 bf16.
// A-frag: A[m=lane&15][k=quad*8+j]; B-frag: B[k=quad*8+j][n=lane&15];
// C/D:    col=lane&15, row=quad*4+reg.
// ---------------------------------------------------------------------------
__global__ __launch_bounds__(256) void win_attn(
    const float* __restrict__ x,
    const bf16_t* __restrict__ wq, const bf16_t* __restrict__ wk,
    const bf16_t* __restrict__ wv,
    bf16_t* __restrict__ attn_out)
{
    __shared__ bf16_t smem[7 * 64 * STR];   // 64512 B
    bf16_t* Xs  = smem;                 // slot0; reused as Ps
    bf16_t* Wqs = smem + 1 * 64 * STR;  // slot1; reused as Os
    bf16_t* Wks = smem + 2 * 64 * STR;
    bf16_t* Wvs = smem + 3 * 64 * STR;
    bf16_t* Qs  = smem + 4 * 64 * STR;
    bf16_t* Ks  = smem + 5 * 64 * STR;
    bf16_t* Vt  = smem + 6 * 64 * STR;  // V transposed: Vt[d][m']

    const int bid  = blockIdx.x;
    const int n    = bid / NHEADS, h = bid % NHEADS;
    const int b    = n >> 6, wy = (n >> 3) & 7, wx = n & 7;
    const int tid  = threadIdx.x;
    const int wave = tid >> 6, lane = tid & 63;
    const int c16  = lane & 15, quad = lane >> 4;

    // ---- stage x tile (49 valid rows, rest zero) ----
    {
        const int row = tid >> 2, d0 = (tid & 3) * 16;
        if (row < 49) {
            const int iy = row / 7, ix = row % 7;
            const float* src = x + (size_t)((b * 56 + wy * 7 + iy) * 56 + wx * 7 + ix) * 768
                                 + h * 64 + d0;
            #pragma unroll
            for (int i = 0; i < 2; i++) {
                fx4 v0 = *(const fx4*)(src + i * 8);
                fx4 v1 = *(const fx4*)(src + i * 8 + 4);
                bx8 t;
                #pragma unroll
                for (int j = 0; j < 4; j++) { t[j] = (bf16_t)v0[j]; t[4 + j] = (bf16_t)v1[j]; }
                *(bx8*)&Xs[row * STR + d0 + i * 8] = t;
            }
        } else {
            bx8 z = {};
            *(bx8*)&Xs[row * STR + d0]     = z;
            *(bx8*)&Xs[row * STR + d0 + 8] = z;
        }
    }
    // ---- stage per-head weights (already bf16), row-major (e, d) ----
    {
        const int e = tid >> 2, d0 = (tid & 3) * 16;
        const size_t g = (size_t)h * 4096 + e * 64 + d0;
        #pragma unroll
        for (int i = 0; i < 2; i++) {
            *(bx8*)&Wqs[e * STR + d0 + i * 8] = *(const bx8*)&wq[g + i * 8];
            *(bx8*)&Wks[e * STR + d0 + i * 8] = *(const bx8*)&wk[g + i * 8];
            *(bx8*)&Wvs[e * STR + d0 + i * 8] = *(const bx8*)&wv[g + i * 8];
        }
    }
    __syncthreads();

    // ---- Q = X Wq^T, K = X Wk^T, V = X Wv^T  (64x64, K=64) ----
    // Wave w owns rows [16w,16w+16); 4 col tiles each.
    fx4 aq[4], ak[4], av[4];
    #pragma unroll
    for (int t = 0; t < 4; t++) { aq[t] = {}; ak[t] = {}; av[t] = {}; }
    #pragma unroll
    for (int kc = 0; kc < 2; kc++) {
        const bx8 a = *(const bx8*)&Xs[(wave * 16 + c16) * STR + kc * 32 + quad * 8];
        #pragma unroll
        for (int t = 0; t < 4; t++) {
            const int r = (t * 16 + c16) * STR + kc * 32 + quad * 8;
            aq[t] = __builtin_amdgcn_mfma_f32_16x16x32_bf16(a, *(const bx8*)&Wqs[r], aq[t], 0, 0, 0);
            ak[t] = __builtin_amdgcn_mfma_f32_16x16x32_bf16(a, *(const bx8*)&Wks[r], ak[t], 0, 0, 0);
            av[t] = __builtin_amdgcn_mfma_f32_16x16x32_bf16(a, *(const bx8*)&Wvs[r], av[t], 0, 0, 0);
        }
    }
    #pragma unroll
    for (int t = 0; t < 4; t++) {
        #pragma unroll
        for (int r = 0; r < 4; r++) {
            const int row = wave * 16 + quad * 4 + r, col = t * 16 + c16;
            Qs[row * STR + col] = (bf16_t)aq[t][r];
            Ks[row * STR + col] = (bf16_t)ak[t][r];
            Vt[col * STR + row] = (bf16_t)av[t][r];   // transposed store
        }
    }
    __syncthreads();

    // ---- S = Q K^T * 0.125, mask cols >= 49, online row softmax ----
    fx4 s[4];
    #pragma unroll
    for (int t = 0; t < 4; t++) s[t] = {};
    #pragma unroll
    for (int kc = 0; kc < 2; kc++) {
        const bx8 a = *(const bx8*)&Qs[(wave * 16 + c16) * STR + kc * 32 + quad * 8];
        #pragma unroll
        for (int t = 0; t < 4; t++) {
            const bx8 bk = *(const bx8*)&Ks[(t * 16 + c16) * STR + kc * 32 + quad * 8];
            s[t] = __builtin_amdgcn_mfma_f32_16x16x32_bf16(a, bk, s[t], 0, 0, 0);
        }
    }
    float rinv[4];
    #pragma unroll
    for (int r = 0; r < 4; r++) {
        #pragma unroll
        for (int t = 0; t < 4; t++) s[t][r] *= 0.125f;
        if (c16 >= 1) s[3][r] = -1e30f;   // col = 48 + c16 >= 49
        float m = fmaxf(fmaxf(s[0][r], s[1][r]), fmaxf(s[2][r], s[3][r]));
        #pragma unroll
        for (int off = 1; off < 16; off <<= 1) m = fmaxf(m, __shfl_xor(m, off));
        float sum = 0.f;
        #pragma unroll
        for (int t = 0; t < 4; t++) {
            const float e = __expf(s[t][r] - m);
            s[t][r] = e;
            sum += e;
        }
        #pragma unroll
        for (int off = 1; off < 16; off <<= 1) sum += __shfl_xor(sum, off);
        rinv[r] = 1.0f / sum;
    }
    // P (unnormalized exp) -> LDS in A-operand-friendly row-major layout
    bf16_t* Ps = Xs;
    #pragma unroll
    for (int t = 0; t < 4; t++) {
        #pragma unroll
        for (int r = 0; r < 4; r++)
            Ps[(wave * 16 + quad * 4 + r) * STR + t * 16 + c16] = (bf16_t)s[t][r];
    }
    __syncthreads();

    // ---- O = P V (row-rescaled by 1/sum at the end) ----
    fx4 o[4];
    #pragma unroll
    for (int t = 0; t < 4; t++) o[t] = {};
    #pragma unroll
    for (int kc = 0; kc < 2; kc++) {
        const bx8 a = *(const bx8*)&Ps[(wave * 16 + c16) * STR + kc * 32 + quad * 8];
        #pragma unroll
        for (int t = 0; t < 4; t++) {
            const bx8 bv = *(const bx8*)&Vt[(t * 16 + c16) * STR + kc * 32 + quad * 8];
            o[t] = __builtin_amdgcn_mfma_f32_16x16x32_bf16(a, bv, o[t], 0, 0, 0);
        }
    }
    bf16_t* Os = Wqs;  // slot1 free since phase-1 barrier
    #pragma unroll
    for (int t = 0; t < 4; t++) {
        #pragma unroll
        for (int r = 0; r < 4; r++) {
            const int row = wave * 16 + quad * 4 + r;
            Os[row * STR + t * 16 + c16] = (bf16_t)(o[t][r] * rinv[r]);
        }
    }
    __syncthreads();

    // ---- store O (49x64) to attn_out[(n*49+l)*768 + h*64 + d], vectorized ----
    const size_t obase = (size_t)n * 49 * 768 + (size_t)h * 64;
    for (int c = tid; c < 392; c += 256) {   // 49 rows * 8 chunks
        const int l = c >> 3, d0 = (c & 7) * 8;
        *(bx8*)&attn_out[obase + (size_t)l * 768 + d0] = *(const bx8*)&Os[l * STR + d0];
    }
}

// ---------------------------------------------------------------------------
// y = attn(100352x768, bf16) @ Wo^T(768x768, bf16) + bo.  128x128 tiles, BK=64.
// grid (6, 784): n-blocks fastest so A-tile rows stay hot in L2.
// ---------------------------------------------------------------------------
__global__ __launch_bounds__(256) void proj(
    const bf16_t* __restrict__ attn, const bf16_t* __restrict__ wo,
    const float* __restrict__ bo, float* __restrict__ y)
{
    __shared__ bf16_t As[128 * STR];   // 18432 B
    __shared__ bf16_t Bs[128 * STR];
    const int n0 = blockIdx.x * 128;
    const int m0 = blockIdx.y * 128;
    const int tid  = threadIdx.x;
    const int wave = tid >> 6, lane = tid & 63;
    const int c16  = lane & 15, quad = lane >> 4;
    const int wy = wave >> 1, wx = wave & 1;

    fx4 acc[4][4];
    #pragma unroll
    for (int mt = 0; mt < 4; mt++)
        #pragma unroll
        for (int nt = 0; nt < 4; nt++) acc[mt][nt] = {};

    for (int k0 = 0; k0 < 768; k0 += 64) {
        __syncthreads();
        #pragma unroll
        for (int i = 0; i < 4; i++) {           // 1024 16B chunks, 4 per thread
            const int c = tid + i * 256;
            const int row = c >> 3, cd = (c & 7) * 8;
            *(bx8*)&As[row * STR + cd] = *(const bx8*)&attn[(size_t)(m0 + row) * 768 + k0 + cd];
            *(bx8*)&Bs[row * STR + cd] = *(const bx8*)&wo[(size_t)(n0 + row) * 768 + k0 + cd];
        }
        __syncthreads();
        #pragma unroll
        for (int kc = 0; kc < 2; kc++) {
            bx8 af[4], bfr[4];
            #pragma unroll
            for (int mt = 0; mt < 4; mt++)
                af[mt] = *(const bx8*)&As[(wy * 64 + mt * 16 + c16) * STR + kc * 32 + quad * 8];
            #pragma unroll
            for (int nt = 0; nt < 4; nt++)
                bfr[nt] = *(const bx8*)&Bs[(wx * 64 + nt * 16 + c16) * STR + kc * 32 + quad * 8];
            #pragma unroll
            for (int mt = 0; mt < 4; mt++)
                #pragma unroll
                for (int nt = 0; nt < 4; nt++)
                    acc[mt][nt] = __builtin_amdgcn_mfma_f32_16x16x32_bf16(af[mt], bfr[nt], acc[mt][nt], 0, 0, 0);
        }
    }
    #pragma unroll
    for (int nt = 0; nt < 4; nt++) {
        const int col = n0 + wx * 64 + nt * 16 + c16;
        const float bias = bo[col];
        #pragma unroll
        for (int mt = 0; mt < 4; mt++)
            #pragma unroll
            for (int r = 0; r < 4; r++) {
                const int row = m0 + wy * 64 + mt * 16 + quad * 4 + r;
                y[(size_t)row * 768 + col] = acc[mt][nt][r] + bias;
            }
    }
}

extern "C" void kernel_launch(void* const* d_in, const int* in_sizes, int n_in,
                              void* d_out, int out_size, void* d_ws, size_t ws_size,
                              hipStream_t stream)
{
    const float* x  = (const float*)d_in[0];
    const float* Wq = (const float*)d_in[1];
    const float* Wk = (const float*)d_in[2];
    const float* Wv = (const float*)d_in[3];
    const float* Wo = (const float*)d_in[4];
    const float* bo = (const float*)d_in[5];
    float* y = (float*)d_out;

    bf16_t* ws   = (bf16_t*)d_ws;
    bf16_t* wq_b = ws;
    bf16_t* wk_b = ws + 49152;
    bf16_t* wv_b = ws + 98304;
    bf16_t* wo_b = ws + 147456;
    bf16_t* attn = ws + 737280;     // 100352*768 bf16 = 154 MB

    convert_w<<<360, 256, 0, stream>>>(Wq, Wk, Wv, Wo, ws);
    win_attn<<<24576, 256, 0, stream>>>(x, wq_b, wk_b, wv_b, attn);
    proj<<<dim3(6, 784), 256, 0, stream>>>(attn, wo_b, bo, y);
}